// Round 11
// baseline (387.439 us; speedup 1.0000x reference)
//
#include <hip/hip_runtime.h>
#include <hip/hip_bf16.h>
#include <hip/hip_cooperative_groups.h>

namespace cg = cooperative_groups;

#define MODEL_DIM 256
#define HIST 8
#define HID 512
#define NNEUR 64
#define IN_DIM 2304   // MODEL_DIM * (1 + HIST)
#define BATCH 32

__device__ __forceinline__ float geluf(float x) {
    return 0.5f * x * (1.0f + erff(x * 0.70710678118654752440f));
}
__device__ __forceinline__ float f4c(const float4& v, int j) {
    switch (j) { case 0: return v.x; case 1: return v.y; case 2: return v.z; default: return v.w; }
}

// ---------------------------------------------------------------------------
// Single fused cooperative kernel. Grid 512 x 256 (launch_bounds(256,4):
// 4 blocks/CU capacity -> 1024 co-resident >= 512 grid, 2x margin).
// Phase bodies are the proven r9 kernels verbatim.
//  P0: proj = emb @ Wp + bp                (blocks 0..31)
//  P1: hist stream unit + proj GEMM unit   (1 + 1 per block)
//  P2: layer2                              (2 units per block)
//  P3: layer3                              (2 units per block)
//  P4: sum + bias + LN + oscillator + out  (1 unit per block)
// ---------------------------------------------------------------------------
__global__ __launch_bounds__(256, 4) void k_fused(
        const float* __restrict__ emb, const float* __restrict__ pre,
        const float* __restrict__ Wp,  const float* __restrict__ bp,
        const float* __restrict__ W1,  const float* __restrict__ b1,
        const float* __restrict__ W2,  const float* __restrict__ b2,
        const float* __restrict__ W3,  const float* __restrict__ b3,
        const float* __restrict__ gamma, const float* __restrict__ beta,
        const int* __restrict__ tick,
        float* __restrict__ proj, float* __restrict__ ph, float* __restrict__ pp,
        float* __restrict__ p2,  float* __restrict__ p3, float* __restrict__ out) {
    cg::grid_group grid = cg::this_grid();
    const int bid = blockIdx.x;
    const int t   = threadIdx.x;
    __shared__ float lds[2048];

    // ---------------- P0: proj (blocks 0..31) ----------------
    if (bid < 32) {
        const float* e = emb + bid * MODEL_DIM;
        float acc = bp[t];
        #pragma unroll 4
        for (int k = 0; k < MODEL_DIM; ++k)
            acc = fmaf(e[k], Wp[(size_t)k * MODEL_DIM + t], acc);
        proj[bid * MODEL_DIM + t] = acc;
    }
    grid.sync();

    // ---------------- P1a: history stream unit (unit = bid) ----------------
    {
        const int n  = bid >> 3;
        const int ks = bid & 7;
        const int c4 = t & 127;            // float4 col group
        const int kh = t >> 7;             // k half (128 each)
        const int k0 = ks * 256;

        lds[t] = pre[k0 + t];
        __syncthreads();

        const float* W = W1 + (size_t)n * IN_DIM * HID
                            + (size_t)(MODEL_DIM + k0 + kh * 128) * HID + c4 * 4;
        float4 a = make_float4(0.f, 0.f, 0.f, 0.f);
        const float* psk = lds + kh * 128;
        #pragma unroll 8
        for (int kk = 0; kk < 128; ++kk) {
            float4 w = *((const float4*)(W + (size_t)kk * HID));
            float s = psk[kk];
            a.x = fmaf(s, w.x, a.x);
            a.y = fmaf(s, w.y, a.y);
            a.z = fmaf(s, w.z, a.z);
            a.w = fmaf(s, w.w, a.w);
        }
        float4* red = (float4*)(lds + 256);     // 128 float4
        if (kh == 1) red[c4] = a;
        __syncthreads();
        if (kh == 0) {
            float4 b4 = red[c4];
            a.x += b4.x; a.y += b4.y; a.z += b4.z; a.w += b4.w;
            *((float4*)(ph + ((size_t)ks * NNEUR + n) * HID + c4 * 4)) = a;
        }
        __syncthreads();                        // lds reused below
    }

    // ---------------- P1b: proj GEMM unit (unit = bid) ----------------
    {
        const int n  = bid >> 3;
        const int ct = (bid >> 2) & 1;
        const int ks = bid & 3;             // K = 64 of the 256 proj rows
        const int cg = t & 63;
        const int rg = t >> 6;
        const int col0 = ct * 256 + cg * 4;
        const int row0 = rg * 8;
        const int k0 = ks * 64;

        float (*xs)[64] = (float(*)[64])lds;     // 32 x 64 slice of proj
        #pragma unroll
        for (int q = 0; q < 2; ++q) {            // 32*16 float4 = 512
            int fi  = t + 256 * q;
            int row = fi >> 4;
            int c4v = fi & 15;
            *((float4*)&xs[row][c4v * 4]) =
                *((const float4*)(proj + (size_t)row * MODEL_DIM + k0 + c4v * 4));
        }
        __syncthreads();

        const float* W = W1 + (size_t)n * IN_DIM * HID + (size_t)k0 * HID + col0;

        float acc[8][4];
        #pragma unroll
        for (int i = 0; i < 8; ++i)
            #pragma unroll
            for (int j = 0; j < 4; ++j) acc[i][j] = 0.0f;

        for (int kg = 0; kg < 64; kg += 4) {
            float4 xv[8];
            #pragma unroll
            for (int i = 0; i < 8; ++i)
                xv[i] = *((const float4*)&xs[row0 + i][kg]);
            #pragma unroll
            for (int j = 0; j < 4; ++j) {
                float4 w = *((const float4*)(W + (size_t)(kg + j) * HID));
                #pragma unroll
                for (int i = 0; i < 8; ++i) {
                    float xvv = f4c(xv[i], j);
                    acc[i][0] = fmaf(xvv, w.x, acc[i][0]);
                    acc[i][1] = fmaf(xvv, w.y, acc[i][1]);
                    acc[i][2] = fmaf(xvv, w.z, acc[i][2]);
                    acc[i][3] = fmaf(xvv, w.w, acc[i][3]);
                }
            }
        }
        float* P = pp + (size_t)(ks * NNEUR + n) * BATCH * HID;
        #pragma unroll
        for (int i = 0; i < 8; ++i)
            *((float4*)(P + (size_t)(row0 + i) * HID + col0)) =
                make_float4(acc[i][0], acc[i][1], acc[i][2], acc[i][3]);
    }
    grid.sync();

    // ---------------- P2: layer2, units bid and bid+512 ----------------
    #pragma unroll 1
    for (int u = bid; u < 1024; u += 512) {
        const int n  = u >> 4;
        const int ct = (u >> 3) & 1;
        const int ks = u & 7;
        const int cg = t & 63;
        const int rg = t >> 6;
        const int col0 = ct * 256 + cg * 4;
        const int row0 = rg * 8;
        const int k0 = ks * 64;

        const size_t slp = (size_t)NNEUR * BATCH * HID;
        const size_t slh = (size_t)NNEUR * HID;

        float (*xs)[64] = (float(*)[64])lds;
        __syncthreads();
        #pragma unroll
        for (int q = 0; q < 2; ++q) {                 // 32*16 float4 = 512
            int fi  = t + 256 * q;
            int row = fi >> 4;
            int c4v = fi & 15;
            const float* a = pp + ((size_t)n * BATCH + row) * HID + k0 + c4v * 4;
            float4 s0 = *((const float4*)(a));
            float4 s1 = *((const float4*)(a + slp));
            float4 s2 = *((const float4*)(a + 2 * slp));
            float4 s3 = *((const float4*)(a + 3 * slp));
            const float* h = ph + (size_t)n * HID + k0 + c4v * 4;
            float4 h0 = *((const float4*)(h));
            float4 h1 = *((const float4*)(h + slh));
            float4 h2 = *((const float4*)(h + 2 * slh));
            float4 h3 = *((const float4*)(h + 3 * slh));
            float4 h4 = *((const float4*)(h + 4 * slh));
            float4 h5 = *((const float4*)(h + 5 * slh));
            float4 h6 = *((const float4*)(h + 6 * slh));
            float4 h7 = *((const float4*)(h + 7 * slh));
            float4 bb = *((const float4*)(b1 + (size_t)n * HID + k0 + c4v * 4));
            *((float4*)&xs[row][c4v * 4]) = make_float4(
                geluf(s0.x+s1.x+s2.x+s3.x + h0.x+h1.x+h2.x+h3.x+h4.x+h5.x+h6.x+h7.x + bb.x),
                geluf(s0.y+s1.y+s2.y+s3.y + h0.y+h1.y+h2.y+h3.y+h4.y+h5.y+h6.y+h7.y + bb.y),
                geluf(s0.z+s1.z+s2.z+s3.z + h0.z+h1.z+h2.z+h3.z+h4.z+h5.z+h6.z+h7.z + bb.z),
                geluf(s0.w+s1.w+s2.w+s3.w + h0.w+h1.w+h2.w+h3.w+h4.w+h5.w+h6.w+h7.w + bb.w));
        }
        __syncthreads();

        const float* W = W2 + (size_t)n * HID * HID + (size_t)k0 * HID + col0;

        float acc[8][4];
        #pragma unroll
        for (int i = 0; i < 8; ++i)
            #pragma unroll
            for (int j = 0; j < 4; ++j) acc[i][j] = 0.0f;

        for (int kg = 0; kg < 64; kg += 4) {
            float4 xv[8];
            #pragma unroll
            for (int i = 0; i < 8; ++i)
                xv[i] = *((const float4*)&xs[row0 + i][kg]);
            #pragma unroll
            for (int j = 0; j < 4; ++j) {
                float4 w = *((const float4*)(W + (size_t)(kg + j) * HID));
                #pragma unroll
                for (int i = 0; i < 8; ++i) {
                    float xvv = f4c(xv[i], j);
                    acc[i][0] = fmaf(xvv, w.x, acc[i][0]);
                    acc[i][1] = fmaf(xvv, w.y, acc[i][1]);
                    acc[i][2] = fmaf(xvv, w.z, acc[i][2]);
                    acc[i][3] = fmaf(xvv, w.w, acc[i][3]);
                }
            }
        }
        float* P = p2 + (size_t)(ks * NNEUR + n) * BATCH * HID;
        #pragma unroll
        for (int i = 0; i < 8; ++i)
            *((float4*)(P + (size_t)(row0 + i) * HID + col0)) =
                make_float4(acc[i][0], acc[i][1], acc[i][2], acc[i][3]);
    }
    grid.sync();

    // ---------------- P3: layer3, units bid and bid+512 ----------------
    #pragma unroll 1
    for (int u = bid; u < 1024; u += 512) {
        const int n  = u >> 4;
        const int ks = u & 15;
        const int cg = t & 63;
        const int rg = t >> 6;
        const int col0 = cg * 4;
        const int row0 = rg * 8;
        const int k0 = ks * 32;

        const size_t sl = (size_t)NNEUR * BATCH * HID;

        float (*xs)[32] = (float(*)[32])lds;
        __syncthreads();
        {                                             // 32*8 float4 = 256
            int row = t >> 3;
            int c4v = t & 7;
            const float* a = p2 + ((size_t)n * BATCH + row) * HID + k0 + c4v * 4;
            float4 s0 = *((const float4*)(a));
            float4 s1 = *((const float4*)(a + sl));
            float4 s2 = *((const float4*)(a + 2 * sl));
            float4 s3 = *((const float4*)(a + 3 * sl));
            float4 s4 = *((const float4*)(a + 4 * sl));
            float4 s5 = *((const float4*)(a + 5 * sl));
            float4 s6 = *((const float4*)(a + 6 * sl));
            float4 s7 = *((const float4*)(a + 7 * sl));
            float4 bb = *((const float4*)(b2 + (size_t)n * HID + k0 + c4v * 4));
            *((float4*)&xs[row][c4v * 4]) = make_float4(
                geluf(s0.x+s1.x+s2.x+s3.x+s4.x+s5.x+s6.x+s7.x + bb.x),
                geluf(s0.y+s1.y+s2.y+s3.y+s4.y+s5.y+s6.y+s7.y + bb.y),
                geluf(s0.z+s1.z+s2.z+s3.z+s4.z+s5.z+s6.z+s7.z + bb.z),
                geluf(s0.w+s1.w+s2.w+s3.w+s4.w+s5.w+s6.w+s7.w + bb.w));
        }
        __syncthreads();

        const float* W = W3 + (size_t)n * HID * MODEL_DIM + (size_t)k0 * MODEL_DIM + col0;

        float acc[8][4];
        #pragma unroll
        for (int i = 0; i < 8; ++i)
            #pragma unroll
            for (int j = 0; j < 4; ++j) acc[i][j] = 0.0f;

        for (int kg = 0; kg < 32; kg += 4) {
            float4 xv[8];
            #pragma unroll
            for (int i = 0; i < 8; ++i)
                xv[i] = *((const float4*)&xs[row0 + i][kg]);
            #pragma unroll
            for (int j = 0; j < 4; ++j) {
                float4 w = *((const float4*)(W + (size_t)(kg + j) * MODEL_DIM));
                #pragma unroll
                for (int i = 0; i < 8; ++i) {
                    float xvv = f4c(xv[i], j);
                    acc[i][0] = fmaf(xvv, w.x, acc[i][0]);
                    acc[i][1] = fmaf(xvv, w.y, acc[i][1]);
                    acc[i][2] = fmaf(xvv, w.z, acc[i][2]);
                    acc[i][3] = fmaf(xvv, w.w, acc[i][3]);
                }
            }
        }
        float* P = p3 + (size_t)(ks * NNEUR + n) * BATCH * MODEL_DIM;
        #pragma unroll
        for (int i = 0; i < 8; ++i)
            *((float4*)(P + (size_t)(row0 + i) * MODEL_DIM + col0)) =
                make_float4(acc[i][0], acc[i][1], acc[i][2], acc[i][3]);
    }
    grid.sync();

    // ---------------- P4: final (unit = bid) ----------------
    {
        const int n  = bid >> 3;
        const int bq = bid & 7;
        const int w  = t >> 6;
        const int lane = t & 63;
        const int b  = bq * 4 + w;

        const size_t par0 = (size_t)n * MODEL_DIM;
        const size_t rowoff = ((size_t)n * BATCH + b) * MODEL_DIM;
        const size_t sl = (size_t)NNEUR * BATCH * MODEL_DIM;

        float y[4];
        #pragma unroll
        for (int j = 0; j < 4; ++j) {
            int d = lane + 64 * j;
            float v = b3[par0 + d];
            #pragma unroll
            for (int s = 0; s < 16; ++s)
                v += p3[s * sl + rowoff + d];
            y[j] = v;
        }
        float s = y[0] + y[1] + y[2] + y[3];
        #pragma unroll
        for (int off = 32; off > 0; off >>= 1) s += __shfl_xor(s, off);
        float mu = s * (1.0f / 256.0f);
        float q = 0.0f;
        #pragma unroll
        for (int j = 0; j < 4; ++j) { float d0 = y[j] - mu; q = fmaf(d0, d0, q); }
        #pragma unroll
        for (int off = 32; off > 0; off >>= 1) q += __shfl_xor(q, off);
        float inv = rsqrtf(q * (1.0f / 256.0f) + 1e-5f);

        const double TWO_PI = 6.283185307179586476925287;
        double freq  = 0.5 * pow(80.0, (double)n * (1.0 / 63.0));
        double phase = fmod((double)n * 2.3571, TWO_PI);
        double tt    = (double)(*tick) * 0.1;
        float mod = (float)(1.0 + 0.5 * sin(TWO_PI * freq * tt + phase));

        #pragma unroll
        for (int j = 0; j < 4; ++j) {
            int d = lane + 64 * j;
            float o = (y[j] - mu) * inv * gamma[par0 + d] + beta[par0 + d];
            o *= mod;
            out[((size_t)b * NNEUR + n) * MODEL_DIM + d] = o;
        }
    }
}

// ---------------------------------------------------------------------------
extern "C" void kernel_launch(void* const* d_in, const int* in_sizes, int n_in,
                              void* d_out, int out_size, void* d_ws, size_t ws_size,
                              hipStream_t stream) {
    const float* emb  = (const float*)d_in[0];
    const float* pre  = (const float*)d_in[1];
    const float* Wp   = (const float*)d_in[2];
    const float* bp   = (const float*)d_in[3];
    const float* W1   = (const float*)d_in[4];
    const float* b1   = (const float*)d_in[5];
    const float* W2   = (const float*)d_in[6];
    const float* b2   = (const float*)d_in[7];
    const float* W3   = (const float*)d_in[8];
    const float* b3   = (const float*)d_in[9];
    const float* gam  = (const float*)d_in[10];
    const float* bet  = (const float*)d_in[11];
    const int* tick   = (const int*)d_in[12];

    float* ws = (float*)d_ws;
    float* proj = ws;                    // 32*256            =    8192 f32
    float* ph = proj + 8192;             // [8][64][512]      =  262144 f32
    float* pp = ph + 262144;             // [4][64][32][512]  = 4194304 f32
    float* p2 = pp + 4194304;            // [8][64][32][512]  = 8388608 f32
    float* p3 = p2 + 8388608;            // [16][64][32][256] = 8388608 f32
    float* out = (float*)d_out;

    void* args[] = {
        (void*)&emb, (void*)&pre, (void*)&Wp, (void*)&bp,
        (void*)&W1, (void*)&b1, (void*)&W2, (void*)&b2,
        (void*)&W3, (void*)&b3, (void*)&gam, (void*)&bet,
        (void*)&tick, (void*)&proj, (void*)&ph, (void*)&pp,
        (void*)&p2, (void*)&p3, (void*)&out
    };
    hipLaunchCooperativeKernel((const void*)k_fused, dim3(512), dim3(256),
                               args, 0, stream);
}

// Round 12
// 175.268 us; speedup vs baseline: 2.2105x; 2.2105x over previous
//
#include <hip/hip_runtime.h>
#include <hip/hip_bf16.h>

#define MODEL_DIM 256
#define HIST 8
#define HID 512
#define NNEUR 64
#define IN_DIM 2304   // MODEL_DIM * (1 + HIST)
#define BATCH 32

__device__ __forceinline__ float geluf(float x) {
    return 0.5f * x * (1.0f + erff(x * 0.70710678118654752440f));
}
__device__ __forceinline__ float f4c(const float4& v, int j) {
    switch (j) { case 0: return v.x; case 1: return v.y; case 2: return v.z; default: return v.w; }
}

// ---------------------------------------------------------------------------
// K0: proj[b][d] = emb[b] @ Wp + bp   (32 x 256)
// ---------------------------------------------------------------------------
__global__ __launch_bounds__(256) void k_build_x(
        const float* __restrict__ emb, const float* __restrict__ pre,
        const float* __restrict__ Wp, const float* __restrict__ bp,
        float* __restrict__ proj) {
    const int b = blockIdx.x;
    const int d = threadIdx.x;

    __shared__ float e[MODEL_DIM];
    e[d] = emb[b * MODEL_DIM + d];
    __syncthreads();

    float acc = bp[d];
    #pragma unroll 4
    for (int k = 0; k < MODEL_DIM; ++k)
        acc = fmaf(e[k], Wp[(size_t)k * MODEL_DIM + d], acc);
    proj[b * MODEL_DIM + d] = acc;
}

// ---------------------------------------------------------------------------
// K1h: history GEMV, contiguous-per-wave stream.
// grid 1024 = n(64) x ks(16: K=128 hist rows). block 256 = 4 waves.
// wave w owns rows k0+32w..+32 (each row = 2KB, read whole row per wave:
// lane l -> cols 8l..8l+7). Wave streams 64KB fully contiguous.
// Cross-wave reduce in LDS. ph[16][64][512] f32
// ---------------------------------------------------------------------------
__global__ __launch_bounds__(256, 4) void k_hist(
        const float* __restrict__ pre, const float* __restrict__ W1,
        float* __restrict__ ph) {
    const int n  = blockIdx.x >> 4;
    const int ks = blockIdx.x & 15;
    const int t  = threadIdx.x;
    const int w  = t >> 6;
    const int l  = t & 63;
    const int k0 = ks * 128;

    __shared__ float ps[128];
    __shared__ float red[4][512];
    if (t < 128) ps[t] = pre[k0 + t];
    __syncthreads();

    const float* W = W1 + (size_t)n * IN_DIM * HID
                        + (size_t)(MODEL_DIM + k0 + w * 32) * HID + l * 8;
    const float* pw = ps + w * 32;

    float4 a0 = make_float4(0.f, 0.f, 0.f, 0.f);
    float4 a1 = make_float4(0.f, 0.f, 0.f, 0.f);
    #pragma unroll 4
    for (int kk = 0; kk < 32; ++kk) {
        float4 w0 = *((const float4*)(W + (size_t)kk * HID));
        float4 w1 = *((const float4*)(W + (size_t)kk * HID + 4));
        float s = pw[kk];
        a0.x = fmaf(s, w0.x, a0.x); a0.y = fmaf(s, w0.y, a0.y);
        a0.z = fmaf(s, w0.z, a0.z); a0.w = fmaf(s, w0.w, a0.w);
        a1.x = fmaf(s, w1.x, a1.x); a1.y = fmaf(s, w1.y, a1.y);
        a1.z = fmaf(s, w1.z, a1.z); a1.w = fmaf(s, w1.w, a1.w);
    }
    *((float4*)&red[w][l * 8])     = a0;
    *((float4*)&red[w][l * 8 + 4]) = a1;
    __syncthreads();

    if (t < 128) {
        const int c = t * 4;
        float4 r0 = *((const float4*)&red[0][c]);
        float4 r1 = *((const float4*)&red[1][c]);
        float4 r2 = *((const float4*)&red[2][c]);
        float4 r3 = *((const float4*)&red[3][c]);
        float4 o = make_float4(r0.x + r1.x + r2.x + r3.x,
                               r0.y + r1.y + r2.y + r3.y,
                               r0.z + r1.z + r2.z + r3.z,
                               r0.w + r1.w + r2.w + r3.w);
        *((float4*)(ph + ((size_t)ks * NNEUR + n) * HID + c)) = o;
    }
}

// ---------------------------------------------------------------------------
// K1p: proj GEMM (r9 P1b body). grid 512 = n(64) x ct(2) x ks(4: K=64).
// block 256: cg(64->4 cols) x rg(4->8 rows). pp[4][64][32][512] f32
// ---------------------------------------------------------------------------
__global__ __launch_bounds__(256, 4) void k_proj(
        const float* __restrict__ proj, const float* __restrict__ W1,
        float* __restrict__ pp) {
    const int bid = blockIdx.x;
    const int n  = bid >> 3;
    const int ct = (bid >> 2) & 1;
    const int ks = bid & 3;
    const int t  = threadIdx.x;
    const int cg = t & 63;
    const int rg = t >> 6;
    const int col0 = ct * 256 + cg * 4;
    const int row0 = rg * 8;
    const int k0 = ks * 64;

    __shared__ float xs[BATCH][64];
    #pragma unroll
    for (int q = 0; q < 2; ++q) {                 // 32*16 float4 = 512
        int fi  = t + 256 * q;
        int row = fi >> 4;
        int c4v = fi & 15;
        *((float4*)&xs[row][c4v * 4]) =
            *((const float4*)(proj + (size_t)row * MODEL_DIM + k0 + c4v * 4));
    }
    __syncthreads();

    const float* W = W1 + (size_t)n * IN_DIM * HID + (size_t)k0 * HID + col0;

    float acc[8][4];
    #pragma unroll
    for (int i = 0; i < 8; ++i)
        #pragma unroll
        for (int j = 0; j < 4; ++j) acc[i][j] = 0.0f;

    for (int kg = 0; kg < 64; kg += 4) {
        float4 xv[8];
        #pragma unroll
        for (int i = 0; i < 8; ++i)
            xv[i] = *((const float4*)&xs[row0 + i][kg]);
        #pragma unroll
        for (int j = 0; j < 4; ++j) {
            float4 w = *((const float4*)(W + (size_t)(kg + j) * HID));
            #pragma unroll
            for (int i = 0; i < 8; ++i) {
                float xvv = f4c(xv[i], j);
                acc[i][0] = fmaf(xvv, w.x, acc[i][0]);
                acc[i][1] = fmaf(xvv, w.y, acc[i][1]);
                acc[i][2] = fmaf(xvv, w.z, acc[i][2]);
                acc[i][3] = fmaf(xvv, w.w, acc[i][3]);
            }
        }
    }
    float* P = pp + (size_t)(ks * NNEUR + n) * BATCH * HID;
    #pragma unroll
    for (int i = 0; i < 8; ++i)
        *((float4*)(P + (size_t)(row0 + i) * HID + col0)) =
            make_float4(acc[i][0], acc[i][1], acc[i][2], acc[i][3]);
}

// ---------------------------------------------------------------------------
// K2: layer2. h1 = gelu(sum_{s<4} pp[s] + sum_{s<16} ph[s] + b1) staged.
// grid 1024 = n(64) x ct(2) x ks(8: K=64). block 256. p2[8][64][32][512] f32
// ---------------------------------------------------------------------------
__global__ __launch_bounds__(256, 4) void k_layer2(
        const float* __restrict__ pp, const float* __restrict__ ph,
        const float* __restrict__ b1,
        const float* __restrict__ W2, float* __restrict__ p2) {
    const int bid = blockIdx.x;
    const int n  = bid >> 4;
    const int ct = (bid >> 3) & 1;
    const int ks = bid & 7;
    const int t  = threadIdx.x;
    const int cg = t & 63;
    const int rg = t >> 6;
    const int col0 = ct * 256 + cg * 4;
    const int row0 = rg * 8;
    const int k0 = ks * 64;

    const size_t slp = (size_t)NNEUR * BATCH * HID;   // pp slice stride
    const size_t slh = (size_t)NNEUR * HID;           // ph slice stride

    __shared__ float xs[BATCH][64];
    #pragma unroll
    for (int q = 0; q < 2; ++q) {                 // 32*16 float4 = 512
        int fi  = t + 256 * q;
        int row = fi >> 4;
        int c4v = fi & 15;
        const float* a = pp + ((size_t)n * BATCH + row) * HID + k0 + c4v * 4;
        float4 s0 = *((const float4*)(a));
        float4 s1 = *((const float4*)(a + slp));
        float4 s2 = *((const float4*)(a + 2 * slp));
        float4 s3 = *((const float4*)(a + 3 * slp));
        float4 hs = make_float4(0.f, 0.f, 0.f, 0.f);
        const float* h = ph + (size_t)n * HID + k0 + c4v * 4;
        #pragma unroll
        for (int s5 = 0; s5 < 16; ++s5) {
            float4 hv = *((const float4*)(h + (size_t)s5 * slh));
            hs.x += hv.x; hs.y += hv.y; hs.z += hv.z; hs.w += hv.w;
        }
        float4 bb = *((const float4*)(b1 + (size_t)n * HID + k0 + c4v * 4));
        *((float4*)&xs[row][c4v * 4]) = make_float4(
            geluf(s0.x + s1.x + s2.x + s3.x + hs.x + bb.x),
            geluf(s0.y + s1.y + s2.y + s3.y + hs.y + bb.y),
            geluf(s0.z + s1.z + s2.z + s3.z + hs.z + bb.z),
            geluf(s0.w + s1.w + s2.w + s3.w + hs.w + bb.w));
    }
    __syncthreads();

    const float* W = W2 + (size_t)n * HID * HID + (size_t)k0 * HID + col0;

    float acc[8][4];
    #pragma unroll
    for (int i = 0; i < 8; ++i)
        #pragma unroll
        for (int j = 0; j < 4; ++j) acc[i][j] = 0.0f;

    for (int kg = 0; kg < 64; kg += 4) {
        float4 xv[8];
        #pragma unroll
        for (int i = 0; i < 8; ++i)
            xv[i] = *((const float4*)&xs[row0 + i][kg]);
        #pragma unroll
        for (int j = 0; j < 4; ++j) {
            float4 w = *((const float4*)(W + (size_t)(kg + j) * HID));
            #pragma unroll
            for (int i = 0; i < 8; ++i) {
                float xvv = f4c(xv[i], j);
                acc[i][0] = fmaf(xvv, w.x, acc[i][0]);
                acc[i][1] = fmaf(xvv, w.y, acc[i][1]);
                acc[i][2] = fmaf(xvv, w.z, acc[i][2]);
                acc[i][3] = fmaf(xvv, w.w, acc[i][3]);
            }
        }
    }
    float* P = p2 + (size_t)(ks * NNEUR + n) * BATCH * HID;
    #pragma unroll
    for (int i = 0; i < 8; ++i)
        *((float4*)(P + (size_t)(row0 + i) * HID + col0)) =
            make_float4(acc[i][0], acc[i][1], acc[i][2], acc[i][3]);
}

// ---------------------------------------------------------------------------
// K3: layer3. h2 = gelu(sum p2[0..7] + b2) staged. grid 1024 = n(64) x
// ks(16: K=32). block 256: cg(64 -> 4 cols, all 256) x rg(4 -> 8 rows).
// p3[16][64][32][256] f32
// ---------------------------------------------------------------------------
__global__ __launch_bounds__(256, 4) void k_layer3(
        const float* __restrict__ p2, const float* __restrict__ b2,
        const float* __restrict__ W3, float* __restrict__ p3) {
    const int bid = blockIdx.x;
    const int n  = bid >> 4;
    const int ks = bid & 15;
    const int t  = threadIdx.x;
    const int cg = t & 63;
    const int rg = t >> 6;
    const int col0 = cg * 4;
    const int row0 = rg * 8;
    const int k0 = ks * 32;

    const size_t sl = (size_t)NNEUR * BATCH * HID;

    __shared__ float xs[BATCH][32];
    {                                             // 32*8 float4 = 256
        int row = t >> 3;
        int c4v = t & 7;
        const float* a = p2 + ((size_t)n * BATCH + row) * HID + k0 + c4v * 4;
        float4 s0 = *((const float4*)(a));
        float4 s1 = *((const float4*)(a + sl));
        float4 s2 = *((const float4*)(a + 2 * sl));
        float4 s3 = *((const float4*)(a + 3 * sl));
        float4 s4 = *((const float4*)(a + 4 * sl));
        float4 s5 = *((const float4*)(a + 5 * sl));
        float4 s6 = *((const float4*)(a + 6 * sl));
        float4 s7 = *((const float4*)(a + 7 * sl));
        float4 bb = *((const float4*)(b2 + (size_t)n * HID + k0 + c4v * 4));
        *((float4*)&xs[row][c4v * 4]) = make_float4(
            geluf(s0.x+s1.x+s2.x+s3.x+s4.x+s5.x+s6.x+s7.x + bb.x),
            geluf(s0.y+s1.y+s2.y+s3.y+s4.y+s5.y+s6.y+s7.y + bb.y),
            geluf(s0.z+s1.z+s2.z+s3.z+s4.z+s5.z+s6.z+s7.z + bb.z),
            geluf(s0.w+s1.w+s2.w+s3.w+s4.w+s5.w+s6.w+s7.w + bb.w));
    }
    __syncthreads();

    const float* W = W3 + (size_t)n * HID * MODEL_DIM + (size_t)k0 * MODEL_DIM + col0;

    float acc[8][4];
    #pragma unroll
    for (int i = 0; i < 8; ++i)
        #pragma unroll
        for (int j = 0; j < 4; ++j) acc[i][j] = 0.0f;

    for (int kg = 0; kg < 32; kg += 4) {
        float4 xv[8];
        #pragma unroll
        for (int i = 0; i < 8; ++i)
            xv[i] = *((const float4*)&xs[row0 + i][kg]);
        #pragma unroll
        for (int j = 0; j < 4; ++j) {
            float4 w = *((const float4*)(W + (size_t)(kg + j) * MODEL_DIM));
            #pragma unroll
            for (int i = 0; i < 8; ++i) {
                float xvv = f4c(xv[i], j);
                acc[i][0] = fmaf(xvv, w.x, acc[i][0]);
                acc[i][1] = fmaf(xvv, w.y, acc[i][1]);
                acc[i][2] = fmaf(xvv, w.z, acc[i][2]);
                acc[i][3] = fmaf(xvv, w.w, acc[i][3]);
            }
        }
    }
    float* P = p3 + (size_t)(ks * NNEUR + n) * BATCH * MODEL_DIM;
    #pragma unroll
    for (int i = 0; i < 8; ++i)
        *((float4*)(P + (size_t)(row0 + i) * MODEL_DIM + col0)) =
            make_float4(acc[i][0], acc[i][1], acc[i][2], acc[i][3]);
}

// ---------------------------------------------------------------------------
// K4: y = sum(p3[0..15]) + b3 ; LayerNorm ; oscillator mod ; f32 store
// ---------------------------------------------------------------------------
__global__ __launch_bounds__(256) void k_final(
        const float* __restrict__ p3, const float* __restrict__ b3,
        const float* __restrict__ gamma, const float* __restrict__ beta,
        const int* __restrict__ tick, float* __restrict__ out) {
    const int n  = blockIdx.x >> 3;
    const int bq = blockIdx.x & 7;
    const int t  = threadIdx.x;
    const int w  = t >> 6;
    const int lane = t & 63;
    const int b  = bq * 4 + w;

    const size_t par0 = (size_t)n * MODEL_DIM;
    const size_t rowoff = ((size_t)n * BATCH + b) * MODEL_DIM;
    const size_t sl = (size_t)NNEUR * BATCH * MODEL_DIM;

    float y[4];
    #pragma unroll
    for (int j = 0; j < 4; ++j) {
        int d = lane + 64 * j;
        float v = b3[par0 + d];
        #pragma unroll
        for (int s = 0; s < 16; ++s)
            v += p3[s * sl + rowoff + d];
        y[j] = v;
    }
    float s = y[0] + y[1] + y[2] + y[3];
    #pragma unroll
    for (int off = 32; off > 0; off >>= 1) s += __shfl_xor(s, off);
    float mu = s * (1.0f / 256.0f);
    float q = 0.0f;
    #pragma unroll
    for (int j = 0; j < 4; ++j) { float d0 = y[j] - mu; q = fmaf(d0, d0, q); }
    #pragma unroll
    for (int off = 32; off > 0; off >>= 1) q += __shfl_xor(q, off);
    float inv = rsqrtf(q * (1.0f / 256.0f) + 1e-5f);

    const double TWO_PI = 6.283185307179586476925287;
    double freq  = 0.5 * pow(80.0, (double)n * (1.0 / 63.0));
    double phase = fmod((double)n * 2.3571, TWO_PI);
    double tt    = (double)(*tick) * 0.1;
    float mod = (float)(1.0 + 0.5 * sin(TWO_PI * freq * tt + phase));

    #pragma unroll
    for (int j = 0; j < 4; ++j) {
        int d = lane + 64 * j;
        float o = (y[j] - mu) * inv * gamma[par0 + d] + beta[par0 + d];
        o *= mod;
        out[((size_t)b * NNEUR + n) * MODEL_DIM + d] = o;
    }
}

// ---------------------------------------------------------------------------
extern "C" void kernel_launch(void* const* d_in, const int* in_sizes, int n_in,
                              void* d_out, int out_size, void* d_ws, size_t ws_size,
                              hipStream_t stream) {
    const float* emb  = (const float*)d_in[0];
    const float* pre  = (const float*)d_in[1];
    const float* Wp   = (const float*)d_in[2];
    const float* bp   = (const float*)d_in[3];
    const float* W1   = (const float*)d_in[4];
    const float* b1   = (const float*)d_in[5];
    const float* W2   = (const float*)d_in[6];
    const float* b2   = (const float*)d_in[7];
    const float* W3   = (const float*)d_in[8];
    const float* b3   = (const float*)d_in[9];
    const float* gam  = (const float*)d_in[10];
    const float* bet  = (const float*)d_in[11];
    const int* tick   = (const int*)d_in[12];

    float* ws = (float*)d_ws;
    float* proj = ws;                    // 32*256            =    8192 f32
    float* ph = proj + 8192;             // [16][64][512]     =  524288 f32
    float* pp = ph + 524288;             // [4][64][32][512]  = 4194304 f32
    float* p2 = pp + 4194304;            // [8][64][32][512]  = 8388608 f32
    float* p3 = p2 + 8388608;            // [16][64][32][256] = 8388608 f32
    float* out = (float*)d_out;

    k_build_x<<<32,   256, 0, stream>>>(emb, pre, Wp, bp, proj);
    k_hist   <<<1024, 256, 0, stream>>>(pre, W1, ph);
    k_proj   <<<512,  256, 0, stream>>>(proj, W1, pp);
    k_layer2 <<<1024, 256, 0, stream>>>(pp, ph, b1, W2, p2);
    k_layer3 <<<1024, 256, 0, stream>>>(p2, b2, W3, p3);
    k_final  <<<512,  256, 0, stream>>>(p3, b3, gam, bet, tick, out);
}

// Round 14
// 154.903 us; speedup vs baseline: 2.5012x; 1.1315x over previous
//
#include <hip/hip_runtime.h>
#include <hip/hip_bf16.h>

#define MODEL_DIM 256
#define HIST 8
#define HID 512
#define NNEUR 64
#define IN_DIM 2304   // MODEL_DIM * (1 + HIST)
#define BATCH 32

typedef float v4f __attribute__((ext_vector_type(4)));

__device__ __forceinline__ float geluf(float x) {
    return 0.5f * x * (1.0f + erff(x * 0.70710678118654752440f));
}
__device__ __forceinline__ float f4c(const float4& v, int j) {
    switch (j) { case 0: return v.x; case 1: return v.y; case 2: return v.z; default: return v.w; }
}
__device__ __forceinline__ float4 ntload4(const float* p) {
    v4f v = __builtin_nontemporal_load((const v4f*)p);
    return make_float4(v.x, v.y, v.z, v.w);
}

// ---------------------------------------------------------------------------
// K0: proj[b][d] = emb[b] @ Wp + bp   (32 x 256)
// ---------------------------------------------------------------------------
__global__ __launch_bounds__(256) void k_build_x(
        const float* __restrict__ emb, const float* __restrict__ pre,
        const float* __restrict__ Wp, const float* __restrict__ bp,
        float* __restrict__ proj) {
    const int b = blockIdx.x;
    const int d = threadIdx.x;

    __shared__ float e[MODEL_DIM];
    e[d] = emb[b * MODEL_DIM + d];
    __syncthreads();

    float acc = bp[d];
    #pragma unroll 4
    for (int k = 0; k < MODEL_DIM; ++k)
        acc = fmaf(e[k], Wp[(size_t)k * MODEL_DIM + d], acc);
    proj[b * MODEL_DIM + d] = acc;
}

// ---------------------------------------------------------------------------
// K1h: history GEMV at 32 waves/CU (8 blocks/CU).
// grid 2048 = n(64) x ks(16: K=128) x ch(2: 256-col half). block 256.
// wave w owns rows k0+32w..+32; lane l owns 4 cols (1KB/row/wave coalesced).
// ~30 VGPR -> 8 blocks/CU resident. Cross-wave reduce in LDS.
// ph[16][64][512] f32
// ---------------------------------------------------------------------------
__global__ __launch_bounds__(256, 8) void k_hist(
        const float* __restrict__ pre, const float* __restrict__ W1,
        float* __restrict__ ph) {
    const int bid = blockIdx.x;
    const int n  = bid >> 5;
    const int ks = (bid >> 1) & 15;
    const int ch = bid & 1;
    const int t  = threadIdx.x;
    const int w  = t >> 6;
    const int l  = t & 63;
    const int k0 = ks * 128;
    const int cb = ch * 256;

    __shared__ float ps[128];
    __shared__ float red[4][256];
    if (t < 128) ps[t] = pre[k0 + t];
    __syncthreads();

    const float* W = W1 + (size_t)n * IN_DIM * HID
                        + (size_t)(MODEL_DIM + k0 + w * 32) * HID + cb + l * 4;
    const float* pw = ps + w * 32;

    float4 a = make_float4(0.f, 0.f, 0.f, 0.f);
    #pragma unroll 8
    for (int kk = 0; kk < 32; ++kk) {
        float4 wv = ntload4(W + (size_t)kk * HID);
        float s = pw[kk];
        a.x = fmaf(s, wv.x, a.x);
        a.y = fmaf(s, wv.y, a.y);
        a.z = fmaf(s, wv.z, a.z);
        a.w = fmaf(s, wv.w, a.w);
    }
    *((float4*)&red[w][l * 4]) = a;
    __syncthreads();

    if (t < 64) {
        const int c = t * 4;
        float4 r0 = *((const float4*)&red[0][c]);
        float4 r1 = *((const float4*)&red[1][c]);
        float4 r2 = *((const float4*)&red[2][c]);
        float4 r3 = *((const float4*)&red[3][c]);
        float4 o = make_float4(r0.x + r1.x + r2.x + r3.x,
                               r0.y + r1.y + r2.y + r3.y,
                               r0.z + r1.z + r2.z + r3.z,
                               r0.w + r1.w + r2.w + r3.w);
        *((float4*)(ph + ((size_t)ks * NNEUR + n) * HID + cb + c)) = o;
    }
}

// ---------------------------------------------------------------------------
// K1p: proj GEMM. grid 512 = n(64) x ct(2) x ks(4: K=64).
// block 256: cg(64->4 cols) x rg(4->8 rows). pp[4][64][32][512] f32
// ---------------------------------------------------------------------------
__global__ __launch_bounds__(256, 4) void k_proj(
        const float* __restrict__ proj, const float* __restrict__ W1,
        float* __restrict__ pp) {
    const int bid = blockIdx.x;
    const int n  = bid >> 3;
    const int ct = (bid >> 2) & 1;
    const int ks = bid & 3;
    const int t  = threadIdx.x;
    const int cg = t & 63;
    const int rg = t >> 6;
    const int col0 = ct * 256 + cg * 4;
    const int row0 = rg * 8;
    const int k0 = ks * 64;

    __shared__ float xs[BATCH][64];
    #pragma unroll
    for (int q = 0; q < 2; ++q) {                 // 32*16 float4 = 512
        int fi  = t + 256 * q;
        int row = fi >> 4;
        int c4v = fi & 15;
        *((float4*)&xs[row][c4v * 4]) =
            *((const float4*)(proj + (size_t)row * MODEL_DIM + k0 + c4v * 4));
    }
    __syncthreads();

    const float* W = W1 + (size_t)n * IN_DIM * HID + (size_t)k0 * HID + col0;

    float acc[8][4];
    #pragma unroll
    for (int i = 0; i < 8; ++i)
        #pragma unroll
        for (int j = 0; j < 4; ++j) acc[i][j] = 0.0f;

    for (int kg = 0; kg < 64; kg += 4) {
        float4 xv[8];
        #pragma unroll
        for (int i = 0; i < 8; ++i)
            xv[i] = *((const float4*)&xs[row0 + i][kg]);
        #pragma unroll
        for (int j = 0; j < 4; ++j) {
            float4 w = ntload4(W + (size_t)(kg + j) * HID);
            #pragma unroll
            for (int i = 0; i < 8; ++i) {
                float xvv = f4c(xv[i], j);
                acc[i][0] = fmaf(xvv, w.x, acc[i][0]);
                acc[i][1] = fmaf(xvv, w.y, acc[i][1]);
                acc[i][2] = fmaf(xvv, w.z, acc[i][2]);
                acc[i][3] = fmaf(xvv, w.w, acc[i][3]);
            }
        }
    }
    float* P = pp + (size_t)(ks * NNEUR + n) * BATCH * HID;
    #pragma unroll
    for (int i = 0; i < 8; ++i)
        *((float4*)(P + (size_t)(row0 + i) * HID + col0)) =
            make_float4(acc[i][0], acc[i][1], acc[i][2], acc[i][3]);
}

// ---------------------------------------------------------------------------
// K2: layer2. h1 = gelu(sum_{s<4} pp[s] + sum_{s<16} ph[s] + b1) staged.
// grid 1024 = n(64) x ct(2) x ks(8: K=64). block 256. p2[8][64][32][512] f32
// ---------------------------------------------------------------------------
__global__ __launch_bounds__(256, 4) void k_layer2(
        const float* __restrict__ pp, const float* __restrict__ ph,
        const float* __restrict__ b1,
        const float* __restrict__ W2, float* __restrict__ p2) {
    const int bid = blockIdx.x;
    const int n  = bid >> 4;
    const int ct = (bid >> 3) & 1;
    const int ks = bid & 7;
    const int t  = threadIdx.x;
    const int cg = t & 63;
    const int rg = t >> 6;
    const int col0 = ct * 256 + cg * 4;
    const int row0 = rg * 8;
    const int k0 = ks * 64;

    const size_t slp = (size_t)NNEUR * BATCH * HID;   // pp slice stride
    const size_t slh = (size_t)NNEUR * HID;           // ph slice stride

    __shared__ float xs[BATCH][64];
    #pragma unroll
    for (int q = 0; q < 2; ++q) {                 // 32*16 float4 = 512
        int fi  = t + 256 * q;
        int row = fi >> 4;
        int c4v = fi & 15;
        const float* a = pp + ((size_t)n * BATCH + row) * HID + k0 + c4v * 4;
        float4 s0 = *((const float4*)(a));
        float4 s1 = *((const float4*)(a + slp));
        float4 s2 = *((const float4*)(a + 2 * slp));
        float4 s3 = *((const float4*)(a + 3 * slp));
        float4 hs = make_float4(0.f, 0.f, 0.f, 0.f);
        const float* h = ph + (size_t)n * HID + k0 + c4v * 4;
        #pragma unroll
        for (int s5 = 0; s5 < 16; ++s5) {
            float4 hv = *((const float4*)(h + (size_t)s5 * slh));
            hs.x += hv.x; hs.y += hv.y; hs.z += hv.z; hs.w += hv.w;
        }
        float4 bb = *((const float4*)(b1 + (size_t)n * HID + k0 + c4v * 4));
        *((float4*)&xs[row][c4v * 4]) = make_float4(
            geluf(s0.x + s1.x + s2.x + s3.x + hs.x + bb.x),
            geluf(s0.y + s1.y + s2.y + s3.y + hs.y + bb.y),
            geluf(s0.z + s1.z + s2.z + s3.z + hs.z + bb.z),
            geluf(s0.w + s1.w + s2.w + s3.w + hs.w + bb.w));
    }
    __syncthreads();

    const float* W = W2 + (size_t)n * HID * HID + (size_t)k0 * HID + col0;

    float acc[8][4];
    #pragma unroll
    for (int i = 0; i < 8; ++i)
        #pragma unroll
        for (int j = 0; j < 4; ++j) acc[i][j] = 0.0f;

    for (int kg = 0; kg < 64; kg += 4) {
        float4 xv[8];
        #pragma unroll
        for (int i = 0; i < 8; ++i)
            xv[i] = *((const float4*)&xs[row0 + i][kg]);
        #pragma unroll
        for (int j = 0; j < 4; ++j) {
            float4 w = ntload4(W + (size_t)(kg + j) * HID);
            #pragma unroll
            for (int i = 0; i < 8; ++i) {
                float xvv = f4c(xv[i], j);
                acc[i][0] = fmaf(xvv, w.x, acc[i][0]);
                acc[i][1] = fmaf(xvv, w.y, acc[i][1]);
                acc[i][2] = fmaf(xvv, w.z, acc[i][2]);
                acc[i][3] = fmaf(xvv, w.w, acc[i][3]);
            }
        }
    }
    float* P = p2 + (size_t)(ks * NNEUR + n) * BATCH * HID;
    #pragma unroll
    for (int i = 0; i < 8; ++i)
        *((float4*)(P + (size_t)(row0 + i) * HID + col0)) =
            make_float4(acc[i][0], acc[i][1], acc[i][2], acc[i][3]);
}

// ---------------------------------------------------------------------------
// K3: layer3. h2 = gelu(sum p2[0..7] + b2) staged. grid 1024 = n(64) x
// ks(16: K=32). block 256: cg(64 -> 4 cols, all 256) x rg(4 -> 8 rows).
// p3[16][64][32][256] f32
// ---------------------------------------------------------------------------
__global__ __launch_bounds__(256, 4) void k_layer3(
        const float* __restrict__ p2, const float* __restrict__ b2,
        const float* __restrict__ W3, float* __restrict__ p3) {
    const int bid = blockIdx.x;
    const int n  = bid >> 4;
    const int ks = bid & 15;
    const int t  = threadIdx.x;
    const int cg = t & 63;
    const int rg = t >> 6;
    const int col0 = cg * 4;
    const int row0 = rg * 8;
    const int k0 = ks * 32;

    const size_t sl = (size_t)NNEUR * BATCH * HID;

    __shared__ float xs[BATCH][32];
    {                                             // 32*8 float4 = 256
        int row = t >> 3;
        int c4v = t & 7;
        const float* a = p2 + ((size_t)n * BATCH + row) * HID + k0 + c4v * 4;
        float4 s0 = *((const float4*)(a));
        float4 s1 = *((const float4*)(a + sl));
        float4 s2 = *((const float4*)(a + 2 * sl));
        float4 s3 = *((const float4*)(a + 3 * sl));
        float4 s4 = *((const float4*)(a + 4 * sl));
        float4 s5 = *((const float4*)(a + 5 * sl));
        float4 s6 = *((const float4*)(a + 6 * sl));
        float4 s7 = *((const float4*)(a + 7 * sl));
        float4 bb = *((const float4*)(b2 + (size_t)n * HID + k0 + c4v * 4));
        *((float4*)&xs[row][c4v * 4]) = make_float4(
            geluf(s0.x+s1.x+s2.x+s3.x+s4.x+s5.x+s6.x+s7.x + bb.x),
            geluf(s0.y+s1.y+s2.y+s3.y+s4.y+s5.y+s6.y+s7.y + bb.y),
            geluf(s0.z+s1.z+s2.z+s3.z+s4.z+s5.z+s6.z+s7.z + bb.z),
            geluf(s0.w+s1.w+s2.w+s3.w+s4.w+s5.w+s6.w+s7.w + bb.w));
    }
    __syncthreads();

    const float* W = W3 + (size_t)n * HID * MODEL_DIM + (size_t)k0 * MODEL_DIM + col0;

    float acc[8][4];
    #pragma unroll
    for (int i = 0; i < 8; ++i)
        #pragma unroll
        for (int j = 0; j < 4; ++j) acc[i][j] = 0.0f;

    for (int kg = 0; kg < 32; kg += 4) {
        float4 xv[8];
        #pragma unroll
        for (int i = 0; i < 8; ++i)
            xv[i] = *((const float4*)&xs[row0 + i][kg]);
        #pragma unroll
        for (int j = 0; j < 4; ++j) {
            float4 w = ntload4(W + (size_t)(kg + j) * MODEL_DIM);
            #pragma unroll
            for (int i = 0; i < 8; ++i) {
                float xvv = f4c(xv[i], j);
                acc[i][0] = fmaf(xvv, w.x, acc[i][0]);
                acc[i][1] = fmaf(xvv, w.y, acc[i][1]);
                acc[i][2] = fmaf(xvv, w.z, acc[i][2]);
                acc[i][3] = fmaf(xvv, w.w, acc[i][3]);
            }
        }
    }
    float* P = p3 + (size_t)(ks * NNEUR + n) * BATCH * MODEL_DIM;
    #pragma unroll
    for (int i = 0; i < 8; ++i)
        *((float4*)(P + (size_t)(row0 + i) * MODEL_DIM + col0)) =
            make_float4(acc[i][0], acc[i][1], acc[i][2], acc[i][3]);
}

// ---------------------------------------------------------------------------
// K4: y = sum(p3[0..15]) + b3 ; LayerNorm ; oscillator mod ; f32 store
// ---------------------------------------------------------------------------
__global__ __launch_bounds__(256) void k_final(
        const float* __restrict__ p3, const float* __restrict__ b3,
        const float* __restrict__ gamma, const float* __restrict__ beta,
        const int* __restrict__ tick, float* __restrict__ out) {
    const int n  = blockIdx.x >> 3;
    const int bq = blockIdx.x & 7;
    const int t  = threadIdx.x;
    const int w  = t >> 6;
    const int lane = t & 63;
    const int b  = bq * 4 + w;

    const size_t par0 = (size_t)n * MODEL_DIM;
    const size_t rowoff = ((size_t)n * BATCH + b) * MODEL_DIM;
    const size_t sl = (size_t)NNEUR * BATCH * MODEL_DIM;

    float y[4];
    #pragma unroll
    for (int j = 0; j < 4; ++j) {
        int d = lane + 64 * j;
        float v = b3[par0 + d];
        #pragma unroll
        for (int s = 0; s < 16; ++s)
            v += p3[s * sl + rowoff + d];
        y[j] = v;
    }
    float s = y[0] + y[1] + y[2] + y[3];
    #pragma unroll
    for (int off = 32; off > 0; off >>= 1) s += __shfl_xor(s, off);
    float mu = s * (1.0f / 256.0f);
    float q = 0.0f;
    #pragma unroll
    for (int j = 0; j < 4; ++j) { float d0 = y[j] - mu; q = fmaf(d0, d0, q); }
    #pragma unroll
    for (int off = 32; off > 0; off >>= 1) q += __shfl_xor(q, off);
    float inv = rsqrtf(q * (1.0f / 256.0f) + 1e-5f);

    const double TWO_PI = 6.283185307179586476925287;
    double freq  = 0.5 * pow(80.0, (double)n * (1.0 / 63.0));
    double phase = fmod((double)n * 2.3571, TWO_PI);
    double tt    = (double)(*tick) * 0.1;
    float mod = (float)(1.0 + 0.5 * sin(TWO_PI * freq * tt + phase));

    #pragma unroll
    for (int j = 0; j < 4; ++j) {
        int d = lane + 64 * j;
        float o = (y[j] - mu) * inv * gamma[par0 + d] + beta[par0 + d];
        o *= mod;
        out[((size_t)b * NNEUR + n) * MODEL_DIM + d] = o;
    }
}

// ---------------------------------------------------------------------------
extern "C" void kernel_launch(void* const* d_in, const int* in_sizes, int n_in,
                              void* d_out, int out_size, void* d_ws, size_t ws_size,
                              hipStream_t stream) {
    const float* emb  = (const float*)d_in[0];
    const float* pre  = (const float*)d_in[1];
    const float* Wp   = (const float*)d_in[2];
    const float* bp   = (const float*)d_in[3];
    const float* W1   = (const float*)d_in[4];
    const float* b1   = (const float*)d_in[5];
    const float* W2   = (const float*)d_in[6];
    const float* b2   = (const float*)d_in[7];
    const float* W3   = (const float*)d_in[8];
    const float* b3   = (const float*)d_in[9];
    const float* gam  = (const float*)d_in[10];
    const float* bet  = (const float*)d_in[11];
    const int* tick   = (const int*)d_in[12];

    float* ws = (float*)d_ws;
    float* proj = ws;                    // 32*256            =    8192 f32
    float* ph = proj + 8192;             // [16][64][512]     =  524288 f32
    float* pp = ph + 524288;             // [4][64][32][512]  = 4194304 f32
    float* p2 = pp + 4194304;            // [8][64][32][512]  = 8388608 f32
    float* p3 = p2 + 8388608;            // [16][64][32][256] = 8388608 f32
    float* out = (float*)d_out;

    k_build_x<<<32,   256, 0, stream>>>(emb, pre, Wp, bp, proj);
    k_hist   <<<2048, 256, 0, stream>>>(pre, W1, ph);
    k_proj   <<<512,  256, 0, stream>>>(proj, W1, pp);
    k_layer2 <<<1024, 256, 0, stream>>>(pp, ph, b1, W2, p2);
    k_layer3 <<<1024, 256, 0, stream>>>(p2, b2, W3, p3);
    k_final  <<<512,  256, 0, stream>>>(p3, b3, gam, bet, tick, out);
}